// Round 14
// baseline (1210.089 us; speedup 1.0000x reference)
//
#include <hip/hip_runtime.h>
#include <hip/hip_cooperative_groups.h>
namespace cg = cooperative_groups;

typedef unsigned int   u32;
typedef unsigned short u16;

typedef _Float16 h2  __attribute__((ext_vector_type(2)));
typedef _Float16 h8  __attribute__((ext_vector_type(8)));
typedef float    f32x4 __attribute__((ext_vector_type(4)));

#define M_TOK 128

__device__ __forceinline__ u16 f2h_(float f) {
    _Float16 h = (_Float16)f; return __builtin_bit_cast(u16, h);
}
__device__ __forceinline__ float h2f_(u16 b) {
    _Float16 h = __builtin_bit_cast(_Float16, b); return (float)h;
}
__device__ __forceinline__ void acc8(uint4 v, float* s) {
#pragma unroll
    for (int i = 0; i < 4; ++i) {
        u32 w = ((const u32*)&v)[i];
        s[2 * i]     += h2f_((u16)(w & 0xFFFF));
        s[2 * i + 1] += h2f_((u16)(w >> 16));
    }
}

// AWQ nibble order: n&7 = j sits at bit position SH[j]
__constant__ int SHC[8] = {0, 16, 4, 20, 8, 24, 12, 28};

// A-fragment-major layout: elem offset for logical (m, k):
//   kb=k/32, q=(k/8)&3, j=k&7, mt=m/16, l16=m&15
//   off = ((kb*8+mt)*64 + q*16 + l16)*8 + j    (fp16 elements)

// ===========================================================================
// Device-side phase bodies (identical logic to round-13 kernels)
// ===========================================================================

__device__ __forceinline__ void rmsnorm_dev(float* ws4, const float* __restrict__ in,
                                            const float* __restrict__ w,
                                            u16* __restrict__ out, int row) {
    const float* x = in + (size_t)row * 4096;
    float ss = 0.f;
#pragma unroll
    for (int j = 0; j < 16; ++j) {
        float v = x[threadIdx.x + 256 * j];
        ss += v * v;
    }
#pragma unroll
    for (int off = 32; off > 0; off >>= 1) ss += __shfl_down(ss, off, 64);
    if ((threadIdx.x & 63) == 0) ws4[threadIdx.x >> 6] = ss;
    __syncthreads();
    float total = ws4[0] + ws4[1] + ws4[2] + ws4[3];
    float r = rsqrtf(total * (1.f / 4096.f) + 1e-6f);
    const int mt = row >> 4, l16 = row & 15;
#pragma unroll
    for (int c2 = 0; c2 < 2; ++c2) {
        int c = threadIdx.x * 2 + c2;
        int kb = c >> 2, qq = c & 3;
        u16 o8[8];
#pragma unroll
        for (int j = 0; j < 8; ++j) {
            int i = c * 8 + j;
            o8[j] = f2h_(x[i] * r * w[i]);
        }
        *(uint4*)(out + ((size_t)(kb * 8 + mt) * 64 + qq * 16 + l16) * 8) = *(const uint4*)o8;
    }
}

// AWQ GEMM core (round-13 proven): wave = 128m x 32n; block = 4 waves on 4
// distinct 32n strips. A step-tile staged in LDS per block (double-buffered),
// one __syncthreads per 64k step. B per-wave private single buffer (same-wave
// DS in-order). zs packed inline at group boundaries. All VMEM at step TOP,
// consumed at BOTTOM. item = sk*TILES + tile; m204 swizzle over TILES.
__device__ void gemm_dev(char* lds, const u16* __restrict__ A,
                         const int* __restrict__ qz, const float* __restrict__ sc,
                         const int* __restrict__ qw, u16* __restrict__ part,
                         int qws, int qzw, int scw, int N, int K, int kchunk,
                         int TILES, int item) {
    const int tid = threadIdx.x, w = tid >> 6, lane = tid & 63;
    const int q = lane >> 4, l16 = lane & 15;
    const int nwg = TILES, bid = item % TILES;
    const int qq8 = nwg >> 3, r8 = nwg & 7, xcd = bid & 7, boff = bid >> 3;
    const int bx = (xcd < r8 ? xcd * (qq8 + 1) : r8 * (qq8 + 1) + (xcd - r8) * qq8) + boff;
    const int n0w = bx * 128 + w * 32;
    const int pc0 = n0w >> 3;
    const int kp = lane & 31, h = lane >> 5;
    const int sk = item / TILES, kc0 = sk * kchunk, kend = min(kc0 + kchunk, K);

    char* ldsA0 = lds;
    char* ldsA1 = lds + 16384;
    char* myB   = lds + 32768 + w * 4608;
    const char* Ab = (const char*)A;
    const int stoff = w * 4096 + lane * 16;
    const int aoff  = (q * 16 + l16) * 16;
    const int* qws_base = qw + pc0;
    const int* qzp = qz + pc0 + h;
    const float* scp = sc + n0w + h * 8;

    f32x4 acc[8][2] = {};
    uint4 za0, za1, zb0, zb1;

    auto ldraw = [&](int k0) -> uint4 {
        return *(const uint4*)(qws_base + (size_t)(k0 + lane) * qws);
    };
    auto packzs = [&](u32 d, const float* scx, uint4& o0, uint4& o1) {
        u32 r[8];
#pragma unroll
        for (int j = 0; j < 8; ++j) {
            u32 mz = 0xE400u | ((d >> SHC[j]) & 15u);
            r[j] = mz | ((u32)f2h_(scx[j]) << 16);
        }
        o0.x = r[0]; o0.y = r[1]; o0.z = r[2]; o0.w = r[3];
        o1.x = r[4]; o1.y = r[5]; o1.z = r[6]; o1.w = r[7];
    };
    auto loadzs = [&](int g) {
        packzs((u32)qzp[(size_t)g * qzw],     scp + (size_t)g * scw,      za0, za1);
        packzs((u32)qzp[(size_t)g * qzw + 2], scp + (size_t)g * scw + 16, zb0, zb1);
    };
    auto bperm8 = [&](uint4 rv, int* b) {
        const int i0 = kp * 8, i1 = i0 + 4;
        b[0] = __builtin_amdgcn_ds_bpermute(i0, (int)rv.x);
        b[1] = __builtin_amdgcn_ds_bpermute(i0, (int)rv.y);
        b[2] = __builtin_amdgcn_ds_bpermute(i0, (int)rv.z);
        b[3] = __builtin_amdgcn_ds_bpermute(i0, (int)rv.w);
        b[4] = __builtin_amdgcn_ds_bpermute(i1, (int)rv.x);
        b[5] = __builtin_amdgcn_ds_bpermute(i1, (int)rv.y);
        b[6] = __builtin_amdgcn_ds_bpermute(i1, (int)rv.z);
        b[7] = __builtin_amdgcn_ds_bpermute(i1, (int)rv.w);
    };
    auto emit_all = [&](const int* b, char* buf) {
        u32 qd0 = (u32)(h ? b[1] : b[0]);
        u32 qd1 = (u32)(h ? b[5] : b[4]);
        u32 qd2 = (u32)(h ? b[3] : b[2]);
        u32 qd3 = (u32)(h ? b[7] : b[6]);
        auto emit8 = [&](u32 w0, u32 w1, int nb, uint4 z0, uint4 z1) {
            char* bb = buf + kp * 4 + nb * 144;
            u32 w0s = w0 >> 4, w1s = w1 >> 4;
            auto em = [&](int j, u32 a0, u32 a1, int bsel, u32 zsj) {
                h2 mz = __builtin_bit_cast(h2, __builtin_amdgcn_perm(zsj, zsj, 0x01000100u));
                h2 s2 = __builtin_bit_cast(h2, __builtin_amdgcn_perm(zsj, zsj, 0x03020302u));
                u32 t = __builtin_amdgcn_perm(a1, a0, (u32)(bsel | ((bsel + 4) << 16)));
                u32 u = (t & 0x000F000Fu) | 0x64006400u;
                h2 v = (__builtin_bit_cast(h2, u) + mz) * s2;
                *(u32*)(bb + j * 144) = __builtin_bit_cast(u32, v);
            };
            em(0, w0, w1, 0, z0.x);  em(4, w0, w1, 1, z1.x);
            em(1, w0, w1, 2, z0.y);  em(5, w0, w1, 3, z1.y);
            em(2, w0s, w1s, 0, z0.z); em(6, w0s, w1s, 1, z1.z);
            em(3, w0s, w1s, 2, z0.w); em(7, w0s, w1s, 3, z1.w);
        };
        emit8(qd0, qd1, h * 8, za0, za1);
        emit8(qd2, qd3, 16 + h * 8, zb0, zb1);
    };

    // prologue
    loadzs(kc0 >> 7);
    uint4 rv0 = ldraw(kc0);
    uint4 rv_n = {0, 0, 0, 0};
    if (kc0 + 64 < kend) rv_n = ldraw(kc0 + 64);
    {
        const char* gs = Ab + (size_t)(kc0 >> 5) * 8192 + stoff;
        uint4 s0 = *(const uint4*)(gs);
        uint4 s1 = *(const uint4*)(gs + 1024);
        uint4 s2 = *(const uint4*)(gs + 2048);
        uint4 s3 = *(const uint4*)(gs + 3072);
        *(uint4*)(ldsA0 + stoff)        = s0;
        *(uint4*)(ldsA0 + stoff + 1024) = s1;
        *(uint4*)(ldsA0 + stoff + 2048) = s2;
        *(uint4*)(ldsA0 + stoff + 3072) = s3;
    }
    {
        int bp0[8];
        bperm8(rv0, bp0);
        emit_all(bp0, myB);
    }
    if (((kc0 + 64) & 127) == 0 && kc0 + 64 < kend)
        loadzs((kc0 + 64) >> 7);
    __syncthreads();

    // main loop: one __syncthreads per 64k step
    char* cur = ldsA0; char* nxt = ldsA1;
    int bp[8];
    for (int k0 = kc0; k0 < kend; k0 += 64) {
        const bool kn1 = (k0 + 64) < kend, kn2 = (k0 + 128) < kend;
        uint4 s0 = {0,0,0,0}, s1 = {0,0,0,0}, s2 = {0,0,0,0}, s3 = {0,0,0,0};
        if (kn1) {
            const char* gs = Ab + (size_t)((k0 + 64) >> 5) * 8192 + stoff;
            s0 = *(const uint4*)(gs);
            s1 = *(const uint4*)(gs + 1024);
            s2 = *(const uint4*)(gs + 2048);
            s3 = *(const uint4*)(gs + 3072);
        }
        uint4 rv_f = {0, 0, 0, 0};
        if (kn2) rv_f = ldraw(k0 + 128);
        {
            uint4 bvc[2];
#pragma unroll
            for (int nt = 0; nt < 2; ++nt)
                bvc[nt] = *(const uint4*)(myB + (nt * 16 + l16) * 144 + q * 16);
            uint4 afc[8];
#pragma unroll
            for (int mt = 0; mt < 8; ++mt)
                afc[mt] = *(const uint4*)(cur + mt * 1024 + aoff);
            if (kn1) bperm8(rv_n, bp);
#pragma unroll
            for (int mt = 0; mt < 8; ++mt)
#pragma unroll
                for (int nt = 0; nt < 2; ++nt)
                    acc[mt][nt] = __builtin_amdgcn_mfma_f32_16x16x32_f16(
                        __builtin_bit_cast(h8, afc[mt]),
                        __builtin_bit_cast(h8, bvc[nt]),
                        acc[mt][nt], 0, 0, 0);
        }
        {
            uint4 bvc[2];
#pragma unroll
            for (int nt = 0; nt < 2; ++nt)
                bvc[nt] = *(const uint4*)(myB + (nt * 16 + l16) * 144 + 64 + q * 16);
            uint4 afc[8];
#pragma unroll
            for (int mt = 0; mt < 8; ++mt)
                afc[mt] = *(const uint4*)(cur + 8192 + mt * 1024 + aoff);
#pragma unroll
            for (int mt = 0; mt < 8; ++mt)
#pragma unroll
                for (int nt = 0; nt < 2; ++nt)
                    acc[mt][nt] = __builtin_amdgcn_mfma_f32_16x16x32_f16(
                        __builtin_bit_cast(h8, afc[mt]),
                        __builtin_bit_cast(h8, bvc[nt]),
                        acc[mt][nt], 0, 0, 0);
        }
        if (kn1) {
            emit_all(bp, myB);
            *(uint4*)(nxt + stoff)        = s0;
            *(uint4*)(nxt + stoff + 1024) = s1;
            *(uint4*)(nxt + stoff + 2048) = s2;
            *(uint4*)(nxt + stoff + 3072) = s3;
        }
        if (((k0 + 128) & 127) == 0 && (k0 + 128) < kend)
            loadzs((k0 + 128) >> 7);
        __syncthreads();
        rv_n = rv_f;
        char* t = cur; cur = nxt; nxt = t;
    }

    // epilogue: fp16 partial store
    u16* pp = part + (size_t)sk * M_TOK * N;
#pragma unroll
    for (int mt = 0; mt < 8; ++mt)
#pragma unroll
        for (int nt = 0; nt < 2; ++nt) {
            const int n = n0w + nt * 16 + l16;
#pragma unroll
            for (int r = 0; r < 4; ++r) {
                const int m = mt * 16 + q * 4 + r;
                pp[(size_t)m * N + n] = f2h_(acc[mt][nt][r]);
            }
        }
}

__device__ __forceinline__ void r2a_dev(const u16* __restrict__ part, u16* __restrict__ out,
                                        int SK, int bidx) {
    const int idx = bidx * 256 + threadIdx.x;
    const int m = idx >> 9, c = idx & 511;
    float s[8] = {};
    for (int k = 0; k < SK; ++k)
        acc8(*(const uint4*)(part + (size_t)k * 524288 + (size_t)m * 4096 + c * 8), s);
    const int kb = c >> 2, qq = c & 3, mt = m >> 4, l16 = m & 15;
    u16 o8[8];
#pragma unroll
    for (int j = 0; j < 8; ++j) o8[j] = f2h_(s[j]);
    *(uint4*)(out + ((size_t)(kb * 8 + mt) * 64 + qq * 16 + l16) * 8) = *(const uint4*)o8;
}

__device__ __forceinline__ void raf_dev(const u16* __restrict__ part, const float* __restrict__ resin,
                                        float* __restrict__ out, int SK, int bidx) {
    const int idx = bidx * 256 + threadIdx.x;
    const size_t base = (size_t)idx * 8;
    float s[8];
    *(float4*)&s[0] = *(const float4*)(resin + base);
    *(float4*)&s[4] = *(const float4*)(resin + base + 4);
    for (int k = 0; k < SK; ++k)
        acc8(*(const uint4*)(part + (size_t)k * 524288 + base), s);
    *(float4*)(out + base)     = *(const float4*)&s[0];
    *(float4*)(out + base + 4) = *(const float4*)&s[4];
}

__device__ __forceinline__ void rar_dev(float* ws4, const u16* __restrict__ part,
                                        const float* __restrict__ resin,
                                        float* __restrict__ resout, const float* __restrict__ w,
                                        u16* __restrict__ aout, int SK, int row) {
    const int t = threadIdx.x;
    const size_t rb = (size_t)row * 4096;
    float s[16];
    {
        const size_t base = rb + (size_t)t * 16;
        *(float4*)&s[0]  = *(const float4*)(resin + base);
        *(float4*)&s[4]  = *(const float4*)(resin + base + 4);
        *(float4*)&s[8]  = *(const float4*)(resin + base + 8);
        *(float4*)&s[12] = *(const float4*)(resin + base + 12);
        for (int k = 0; k < SK; ++k) {
            const u16* pk = part + (size_t)k * 524288 + base;
            acc8(*(const uint4*)pk, &s[0]);
            acc8(*(const uint4*)(pk + 8), &s[8]);
        }
        float4* ro = (float4*)(resout + base);
        ro[0] = *(float4*)&s[0];  ro[1] = *(float4*)&s[4];
        ro[2] = *(float4*)&s[8];  ro[3] = *(float4*)&s[12];
    }
    float ss = 0.f;
#pragma unroll
    for (int j = 0; j < 16; ++j) ss += s[j] * s[j];
#pragma unroll
    for (int off = 32; off > 0; off >>= 1) ss += __shfl_down(ss, off, 64);
    if ((t & 63) == 0) ws4[t >> 6] = ss;
    __syncthreads();
    float total = ws4[0] + ws4[1] + ws4[2] + ws4[3];
    float r = rsqrtf(total * (1.f / 4096.f) + 1e-6f);
    const int mt = row >> 4, l16 = row & 15;
#pragma unroll
    for (int c2 = 0; c2 < 2; ++c2) {
        const int c = t * 2 + c2;
        const int kb = c >> 2, qq = c & 3;
        u16 o8[8];
#pragma unroll
        for (int j = 0; j < 8; ++j)
            o8[j] = f2h_(s[c2 * 8 + j] * r * w[c * 8 + j]);
        *(uint4*)(aout + ((size_t)(kb * 8 + mt) * 64 + qq * 16 + l16) * 8) = *(const uint4*)o8;
    }
}

__device__ __forceinline__ void silu_dev(const u16* __restrict__ part, u16* __restrict__ act,
                                         int SK, int bidx) {
    const int idx = bidx * 256 + threadIdx.x;
    const int m = idx / 1376, c = idx - m * 1376;
    const int nb = c * 8;
    float g[8] = {}, u[8] = {};
    for (int k = 0; k < SK; ++k) {
        const size_t base = (size_t)k * 2818048 + (size_t)m * 22016 + nb;
        acc8(*(const uint4*)(part + base), g);
        acc8(*(const uint4*)(part + base + 11008), u);
    }
    const int kb = nb >> 5, qq = (nb >> 3) & 3, mt = m >> 4, l16 = m & 15;
    u16 o8[8];
#pragma unroll
    for (int j = 0; j < 8; ++j) {
        float a = g[j] / (1.f + __expf(-g[j])) * u[j];
        o8[j] = f2h_(a);
    }
    *(uint4*)(act + ((size_t)(kb * 8 + mt) * 64 + qq * 16 + l16) * 8) = *(const uint4*)o8;
}

// ===========================================================================
// Cooperative mega-kernel: all 9 phases, grid.sync between (replaces ~5-7us
// launch boundaries with ~1-2us grid syncs). Grid 704 x 256, LDS 51200 ->
// 3 blocks/CU -> 768 slots >= 704 co-resident (coop launch validates).
// ===========================================================================
struct MegaP {
    const float *x, *ln1, *ln2;
    const int *qkv_qz, *o_qz, *gu_qz, *dn_qz;
    const float *qkv_sc, *o_sc, *gu_sc, *dn_sc;
    const int *qkv_qw, *o_qw, *gu_qw, *dn_qw;
    u16 *pbuf, *act, *slot;
    float *res2, *out;
};

__launch_bounds__(256, 3)
__global__ void mega(MegaP p) {
    __shared__ __align__(16) char lds[51200];
    cg::grid_group grid = cg::this_grid();
    const int b = blockIdx.x;

    if (b < 128) rmsnorm_dev((float*)lds, p.x, p.ln1, p.slot, b);        // h1
    grid.sync();
    gemm_dev(lds, p.slot, p.qkv_qz, p.qkv_sc, p.qkv_qw, p.pbuf,          // q
             1536, 1536, 12288, 4096, 4096, 192, 32, b);                 // 704 items
    grid.sync();
    if (b < 256) r2a_dev(p.pbuf, p.slot, 22, b);
    grid.sync();
    gemm_dev(lds, p.slot, p.o_qz, p.o_sc, p.o_qw, p.pbuf,                // attn
             512, 512, 4096, 4096, 4096, 192, 32, b);                    // 704 items
    grid.sync();
    if (b < 128) rar_dev((float*)lds, p.pbuf, p.x, p.res2, p.ln2, p.slot, 22, b);
    grid.sync();
    gemm_dev(lds, p.slot, p.gu_qz, p.gu_sc, p.gu_qw, p.pbuf,             // gate_up
             2752, 2752, 22016, 22016, 4096, 512, 172, b);               // 1376 items
    if (b < 672)
        gemm_dev(lds, p.slot, p.gu_qz, p.gu_sc, p.gu_qw, p.pbuf,
                 2752, 2752, 22016, 22016, 4096, 512, 172, b + 704);
    grid.sync();
    if (b < 688) silu_dev(p.pbuf, p.act, 8, b);
    grid.sync();
    gemm_dev(lds, p.act, p.dn_qz, p.dn_sc, p.dn_qw, p.pbuf,              // down
             512, 512, 4096, 4096, 11008, 512, 32, b);                   // 704 items
    grid.sync();
    if (b < 256) raf_dev(p.pbuf, p.res2, p.out, 22, b);
}

// ===========================================================================
// Fallback wrappers (round-13 proven sequence) -- used if coop launch fails
// ===========================================================================
__launch_bounds__(256)
__global__ void rmsnorm_k(const float* __restrict__ in, const float* __restrict__ w,
                          u16* __restrict__ out) {
    __shared__ float ws4[4];
    rmsnorm_dev(ws4, in, w, out, blockIdx.x);
}

__launch_bounds__(256, 3)
__global__ void gemm_awq(const u16* __restrict__ A,
                         const int* __restrict__ qz, const float* __restrict__ sc,
                         const int* __restrict__ qw, u16* __restrict__ part,
                         int qws, int qzw, int scw, int N, int K, int kchunk) {
    __shared__ __align__(16) char lds[51200];
    gemm_dev(lds, A, qz, sc, qw, part, qws, qzw, scw, N, K, kchunk,
             gridDim.x, blockIdx.y * gridDim.x + blockIdx.x);
}

__launch_bounds__(256)
__global__ void reduce_to_afrag(const u16* __restrict__ part, u16* __restrict__ out, int SK) {
    r2a_dev(part, out, SK, blockIdx.x);
}

__launch_bounds__(256)
__global__ void reduce_add_f32(const u16* __restrict__ part, const float* __restrict__ resin,
                               float* __restrict__ out, int SK) {
    raf_dev(part, resin, out, SK, blockIdx.x);
}

__launch_bounds__(256)
__global__ void reduce_add_rms(const u16* __restrict__ part, const float* __restrict__ resin,
                               float* __restrict__ resout, const float* __restrict__ w,
                               u16* __restrict__ aout, int SK) {
    __shared__ float ws4[4];
    rar_dev(ws4, part, resin, resout, w, aout, SK, blockIdx.x);
}

__launch_bounds__(256)
__global__ void silu_mul(const u16* __restrict__ part, u16* __restrict__ act, int SK) {
    silu_dev(part, act, SK, blockIdx.x);
}

// ---------------------------------------------------------------------------
extern "C" void kernel_launch(void* const* d_in, const int* in_sizes, int n_in,
                              void* d_out, int out_size, void* d_ws, size_t ws_size,
                              hipStream_t stream) {
    const float* x      = (const float*)d_in[0];
    const float* ln1_w  = (const float*)d_in[1];
    const float* ln2_w  = (const float*)d_in[2];
    const int*   qkv_qw = (const int*)d_in[3];
    const int*   qkv_qz = (const int*)d_in[4];
    const float* qkv_sc = (const float*)d_in[5];
    const int*   o_qw   = (const int*)d_in[6];
    const int*   o_qz   = (const int*)d_in[7];
    const float* o_sc   = (const float*)d_in[8];
    const int*   gu_qw  = (const int*)d_in[9];
    const int*   gu_qz  = (const int*)d_in[10];
    const float* gu_sc  = (const float*)d_in[11];
    const int*   dn_qw  = (const int*)d_in[12];
    const int*   dn_qz  = (const int*)d_in[13];
    const float* dn_sc  = (const float*)d_in[14];
    float* out = (float*)d_out;

    // ws layout
    char* ws = (char*)d_ws;
    u16*   pbuf = (u16*)(ws);                 // partials: max 45.09 MB (gu SK8)
    u16*   act  = (u16*)(ws + 47906816);      // 2.75 MB fp16 (Afrag)
    float* res2 = (float*)(ws + 50724864);    // 2 MB fp32
    u16*   slot = (u16*)(ws + 52822016);      // 1 MB fp16 Afrag (h1/qb/h2)

    MegaP p;
    p.x = x; p.ln1 = ln1_w; p.ln2 = ln2_w;
    p.qkv_qz = qkv_qz; p.o_qz = o_qz; p.gu_qz = gu_qz; p.dn_qz = dn_qz;
    p.qkv_sc = qkv_sc; p.o_sc = o_sc; p.gu_sc = gu_sc; p.dn_sc = dn_sc;
    p.qkv_qw = qkv_qw; p.o_qw = o_qw; p.gu_qw = gu_qw; p.dn_qw = dn_qw;
    p.pbuf = pbuf; p.act = act; p.slot = slot; p.res2 = res2; p.out = out;

    void* kargs[] = {&p};
    hipError_t e = hipLaunchCooperativeKernel((void*)mega, dim3(704), dim3(256),
                                              kargs, 0, stream);
    if (e != hipSuccess) {
        (void)hipGetLastError();   // clear, run proven round-13 sequence
        rmsnorm_k<<<128, 256, 0, stream>>>(x, ln1_w, slot);
        gemm_awq<<<dim3(32, 22), 256, 0, stream>>>(slot, qkv_qz, qkv_sc, qkv_qw, pbuf,
                                                   1536, 1536, 12288, 4096, 4096, 192);
        reduce_to_afrag<<<256, 256, 0, stream>>>(pbuf, slot, 22);
        gemm_awq<<<dim3(32, 22), 256, 0, stream>>>(slot, o_qz, o_sc, o_qw, pbuf,
                                                   512, 512, 4096, 4096, 4096, 192);
        reduce_add_rms<<<128, 256, 0, stream>>>(pbuf, x, res2, ln2_w, slot, 22);
        gemm_awq<<<dim3(172, 8), 256, 0, stream>>>(slot, gu_qz, gu_sc, gu_qw, pbuf,
                                                   2752, 2752, 22016, 22016, 4096, 512);
        silu_mul<<<688, 256, 0, stream>>>(pbuf, act, 8);
        gemm_awq<<<dim3(32, 22), 256, 0, stream>>>(act, dn_qz, dn_sc, dn_qw, pbuf,
                                                   512, 512, 4096, 4096, 11008, 512);
        reduce_add_f32<<<256, 256, 0, stream>>>(pbuf, res2, out, 22);
    }
}

// Round 15
// 274.451 us; speedup vs baseline: 4.4091x; 4.4091x over previous
//
#include <hip/hip_runtime.h>

typedef unsigned int   u32;
typedef unsigned short u16;

typedef _Float16 h2  __attribute__((ext_vector_type(2)));
typedef _Float16 h8  __attribute__((ext_vector_type(8)));
typedef float    f32x4 __attribute__((ext_vector_type(4)));

#define M_TOK 128

__device__ __forceinline__ u16 f2h_(float f) {
    _Float16 h = (_Float16)f; return __builtin_bit_cast(u16, h);
}
__device__ __forceinline__ float h2f_(u16 b) {
    _Float16 h = __builtin_bit_cast(_Float16, b); return (float)h;
}
__device__ __forceinline__ void acc8(uint4 v, float* s) {
#pragma unroll
    for (int i = 0; i < 4; ++i) {
        u32 w = ((const u32*)&v)[i];
        s[2 * i]     += h2f_((u16)(w & 0xFFFF));
        s[2 * i + 1] += h2f_((u16)(w >> 16));
    }
}

// AWQ nibble order: n&7 = j sits at bit position SH[j]
__constant__ int SHC[8] = {0, 16, 4, 20, 8, 24, 12, 28};

// A-fragment-major layout: elem offset for logical (m, k):
//   kb=k/32, q=(k/8)&3, j=k&7, mt=m/16, l16=m&15
//   off = ((kb*8+mt)*64 + q*16 + l16)*8 + j    (fp16 elements)
// => per 32-k block the 8 KB region [kb*8192, kb*8192+8192) bytes is
//    contiguous; a 64-k step = two contiguous 8 KB blobs.

// ---------------------------------------------------------------------------
// RMSNorm: one block per token row, fp32 in -> fp16 out in Afrag layout
// ---------------------------------------------------------------------------
__launch_bounds__(256)
__global__ void rmsnorm_k(const float* __restrict__ in, const float* __restrict__ w,
                          u16* __restrict__ out) {
    const int row = blockIdx.x;
    const float* x = in + (size_t)row * 4096;
    float ss = 0.f;
#pragma unroll
    for (int j = 0; j < 16; ++j) {
        float v = x[threadIdx.x + 256 * j];
        ss += v * v;
    }
#pragma unroll
    for (int off = 32; off > 0; off >>= 1) ss += __shfl_down(ss, off, 64);
    __shared__ float ws4[4];
    if ((threadIdx.x & 63) == 0) ws4[threadIdx.x >> 6] = ss;
    __syncthreads();
    float total = ws4[0] + ws4[1] + ws4[2] + ws4[3];
    float r = rsqrtf(total * (1.f / 4096.f) + 1e-6f);
    const int mt = row >> 4, l16 = row & 15;
#pragma unroll
    for (int c2 = 0; c2 < 2; ++c2) {
        int c = threadIdx.x * 2 + c2;
        int kb = c >> 2, qq = c & 3;
        u16 o8[8];
#pragma unroll
        for (int j = 0; j < 8; ++j) {
            int i = c * 8 + j;
            o8[j] = f2h_(x[i] * r * w[i]);
        }
        *(uint4*)(out + ((size_t)(kb * 8 + mt) * 64 + qq * 16 + l16) * 8) = *(const uint4*)o8;
    }
}

// ---------------------------------------------------------------------------
// AWQ GEMM -- round-13 proven core (best measured: gu 53us, total 277us).
// Wave = 128m x 32n; block = 4 waves on 4 distinct 32n strips. A step-tile
// staged in LDS per block (double-buffered), one __syncthreads per 64k step.
// B per-wave private single buffer (same-wave DS in-order). zs packed inline
// at group boundaries. All VMEM at step TOP, consumed at BOTTOM.
// ---------------------------------------------------------------------------
__launch_bounds__(256, 3)
__global__ void gemm_awq(const u16* __restrict__ A,
                         const int* __restrict__ qz, const float* __restrict__ sc,
                         const int* __restrict__ qw, u16* __restrict__ part,
                         int qws, int qzw, int scw, int N, int K, int kchunk) {
    __shared__ __align__(16) char lds[51200];   // [0,32K): A dbuf; 32K+w*4608: B

    const int tid = threadIdx.x, w = tid >> 6, lane = tid & 63;
    const int q = lane >> 4, l16 = lane & 15;
    // bijective XCD-chunk swizzle (m204 form)
    const int nwg = gridDim.x, bid = blockIdx.x;
    const int qq8 = nwg >> 3, r8 = nwg & 7, xcd = bid & 7, boff = bid >> 3;
    const int bx = (xcd < r8 ? xcd * (qq8 + 1) : r8 * (qq8 + 1) + (xcd - r8) * qq8) + boff;
    const int n0w = bx * 128 + w * 32;               // this wave's 32n strip
    const int pc0 = n0w >> 3;
    const int kp = lane & 31, h = lane >> 5;
    const int sk = blockIdx.y, kc0 = sk * kchunk, kend = min(kc0 + kchunk, K);

    char* ldsA0 = lds;
    char* ldsA1 = lds + 16384;
    char* myB   = lds + 32768 + w * 4608;
    const char* Ab = (const char*)A;
    const int stoff = w * 4096 + lane * 16;          // staging offset (dst & src)
    const int aoff  = (q * 16 + l16) * 16;           // A-frag lane offset
    const int* qws_base = qw + pc0;
    const int* qzp = qz + pc0 + h;                   // octet h*8 col; +2 for B
    const float* scp = sc + n0w + h * 8;             // octet h*8;   +16 for B

    f32x4 acc[8][2] = {};
    uint4 za0, za1, zb0, zb1;       // current group's packed (mz, sc)

    auto ldraw = [&](int k0) -> uint4 {
        return *(const uint4*)(qws_base + (size_t)(k0 + lane) * qws);
    };
    // inline zs pack: u32 { lo16: fp16(-(1024+z)), hi16: fp16(sc) } per n
    auto packzs = [&](u32 d, const float* scx, uint4& o0, uint4& o1) {
        u32 r[8];
#pragma unroll
        for (int j = 0; j < 8; ++j) {
            u32 mz = 0xE400u | ((d >> SHC[j]) & 15u);
            r[j] = mz | ((u32)f2h_(scx[j]) << 16);
        }
        o0.x = r[0]; o0.y = r[1]; o0.z = r[2]; o0.w = r[3];
        o1.x = r[4]; o1.y = r[5]; o1.z = r[6]; o1.w = r[7];
    };
    auto loadzs = [&](int g) {
        packzs((u32)qzp[(size_t)g * qzw],     scp + (size_t)g * scw,      za0, za1);
        packzs((u32)qzp[(size_t)g * qzw + 2], scp + (size_t)g * scw + 16, zb0, zb1);
    };
    auto bperm8 = [&](uint4 rv, int* b) {
        const int i0 = kp * 8, i1 = i0 + 4;
        b[0] = __builtin_amdgcn_ds_bpermute(i0, (int)rv.x);
        b[1] = __builtin_amdgcn_ds_bpermute(i0, (int)rv.y);
        b[2] = __builtin_amdgcn_ds_bpermute(i0, (int)rv.z);
        b[3] = __builtin_amdgcn_ds_bpermute(i0, (int)rv.w);
        b[4] = __builtin_amdgcn_ds_bpermute(i1, (int)rv.x);
        b[5] = __builtin_amdgcn_ds_bpermute(i1, (int)rv.y);
        b[6] = __builtin_amdgcn_ds_bpermute(i1, (int)rv.z);
        b[7] = __builtin_amdgcn_ds_bpermute(i1, (int)rv.w);
    };
    auto emit_all = [&](const int* b, char* buf) {
        u32 qd0 = (u32)(h ? b[1] : b[0]);
        u32 qd1 = (u32)(h ? b[5] : b[4]);
        u32 qd2 = (u32)(h ? b[3] : b[2]);
        u32 qd3 = (u32)(h ? b[7] : b[6]);
        auto emit8 = [&](u32 w0, u32 w1, int nb, uint4 z0, uint4 z1) {
            char* bb = buf + kp * 4 + nb * 144;
            u32 w0s = w0 >> 4, w1s = w1 >> 4;
            auto em = [&](int j, u32 a0, u32 a1, int bsel, u32 zsj) {
                h2 mz = __builtin_bit_cast(h2, __builtin_amdgcn_perm(zsj, zsj, 0x01000100u));
                h2 s2 = __builtin_bit_cast(h2, __builtin_amdgcn_perm(zsj, zsj, 0x03020302u));
                u32 t = __builtin_amdgcn_perm(a1, a0, (u32)(bsel | ((bsel + 4) << 16)));
                u32 u = (t & 0x000F000Fu) | 0x64006400u;
                h2 v = (__builtin_bit_cast(h2, u) + mz) * s2;
                *(u32*)(bb + j * 144) = __builtin_bit_cast(u32, v);
            };
            em(0, w0, w1, 0, z0.x);  em(4, w0, w1, 1, z1.x);
            em(1, w0, w1, 2, z0.y);  em(5, w0, w1, 3, z1.y);
            em(2, w0s, w1s, 0, z0.z); em(6, w0s, w1s, 1, z1.z);
            em(3, w0s, w1s, 2, z0.w); em(7, w0s, w1s, 3, z1.w);
        };
        emit8(qd0, qd1, h * 8, za0, za1);
        emit8(qd2, qd3, 16 + h * 8, zb0, zb1);
    };

    // ---- prologue: stage A(0) into buf0, dequant B(0), raw ring depth 2 ----
    loadzs(kc0 >> 7);
    uint4 rv0 = ldraw(kc0);
    uint4 rv_n = {0, 0, 0, 0};
    if (kc0 + 64 < kend) rv_n = ldraw(kc0 + 64);
    {
        const char* gs = Ab + (size_t)(kc0 >> 5) * 8192 + stoff;
        uint4 s0 = *(const uint4*)(gs);
        uint4 s1 = *(const uint4*)(gs + 1024);
        uint4 s2 = *(const uint4*)(gs + 2048);
        uint4 s3 = *(const uint4*)(gs + 3072);
        *(uint4*)(ldsA0 + stoff)        = s0;
        *(uint4*)(ldsA0 + stoff + 1024) = s1;
        *(uint4*)(ldsA0 + stoff + 2048) = s2;
        *(uint4*)(ldsA0 + stoff + 3072) = s3;
    }
    {
        int bp0[8];
        bperm8(rv0, bp0);
        emit_all(bp0, myB);
    }
    if (((kc0 + 64) & 127) == 0 && kc0 + 64 < kend)
        loadzs((kc0 + 64) >> 7);        // mid-group chunk start
    __syncthreads();

    // ---- main loop: one __syncthreads per 64k step ----
    char* cur = ldsA0; char* nxt = ldsA1;
    int bp[8];
    for (int k0 = kc0; k0 < kend; k0 += 64) {
        const bool kn1 = (k0 + 64) < kend, kn2 = (k0 + 128) < kend;
        // (1) step TOP: all VMEM issues (consumed at step bottom -> full slack)
        uint4 s0 = {0,0,0,0}, s1 = {0,0,0,0}, s2 = {0,0,0,0}, s3 = {0,0,0,0};
        if (kn1) {
            const char* gs = Ab + (size_t)((k0 + 64) >> 5) * 8192 + stoff;
            s0 = *(const uint4*)(gs);
            s1 = *(const uint4*)(gs + 1024);
            s2 = *(const uint4*)(gs + 2048);
            s3 = *(const uint4*)(gs + 3072);
        }
        uint4 rv_f = {0, 0, 0, 0};
        if (kn2) rv_f = ldraw(k0 + 128);
        // (2) c=0: B frags, A frags from cur, bperms (hide under MFMA), MFMA
        {
            uint4 bvc[2];
#pragma unroll
            for (int nt = 0; nt < 2; ++nt)
                bvc[nt] = *(const uint4*)(myB + (nt * 16 + l16) * 144 + q * 16);
            uint4 afc[8];
#pragma unroll
            for (int mt = 0; mt < 8; ++mt)
                afc[mt] = *(const uint4*)(cur + mt * 1024 + aoff);
            if (kn1) bperm8(rv_n, bp);
#pragma unroll
            for (int mt = 0; mt < 8; ++mt)
#pragma unroll
                for (int nt = 0; nt < 2; ++nt)
                    acc[mt][nt] = __builtin_amdgcn_mfma_f32_16x16x32_f16(
                        __builtin_bit_cast(h8, afc[mt]),
                        __builtin_bit_cast(h8, bvc[nt]),
                        acc[mt][nt], 0, 0, 0);
        }
        // (3) c=1
        {
            uint4 bvc[2];
#pragma unroll
            for (int nt = 0; nt < 2; ++nt)
                bvc[nt] = *(const uint4*)(myB + (nt * 16 + l16) * 144 + 64 + q * 16);
            uint4 afc[8];
#pragma unroll
            for (int mt = 0; mt < 8; ++mt)
                afc[mt] = *(const uint4*)(cur + 8192 + mt * 1024 + aoff);
#pragma unroll
            for (int mt = 0; mt < 8; ++mt)
#pragma unroll
                for (int nt = 0; nt < 2; ++nt)
                    acc[mt][nt] = __builtin_amdgcn_mfma_f32_16x16x32_f16(
                        __builtin_bit_cast(h8, afc[mt]),
                        __builtin_bit_cast(h8, bvc[nt]),
                        acc[mt][nt], 0, 0, 0);
        }
        // (4) produce phase: B(i+1) into private myB (same-wave in-order after
        // the bv reads above); A(i+1) into the OTHER A buffer (nxt)
        if (kn1) {
            emit_all(bp, myB);
            *(uint4*)(nxt + stoff)        = s0;
            *(uint4*)(nxt + stoff + 1024) = s1;
            *(uint4*)(nxt + stoff + 2048) = s2;
            *(uint4*)(nxt + stoff + 3072) = s3;
        }
        if (((k0 + 128) & 127) == 0 && (k0 + 128) < kend)
            loadzs((k0 + 128) >> 7);    // zs(group+1), used next step
        // (5) publish A(i+1) to all waves
        __syncthreads();
        rv_n = rv_f;
        char* t = cur; cur = nxt; nxt = t;
    }

    // ---- epilogue: fp16 partial store ----
    u16* pp = part + (size_t)sk * M_TOK * N;
#pragma unroll
    for (int mt = 0; mt < 8; ++mt)
#pragma unroll
        for (int nt = 0; nt < 2; ++nt) {
            const int n = n0w + nt * 16 + l16;
#pragma unroll
            for (int r = 0; r < 4; ++r) {
                const int m = mt * 16 + q * 4 + r;
                pp[(size_t)m * N + n] = f2h_(acc[mt][nt][r]);
            }
        }
}

// ---------------------------------------------------------------------------
__launch_bounds__(256)
__global__ void reduce_to_afrag(const u16* __restrict__ part, u16* __restrict__ out,
                                int SK) {
    const int idx = blockIdx.x * 256 + threadIdx.x;
    const int m = idx >> 9, c = idx & 511;
    float s[8] = {};
    for (int k = 0; k < SK; ++k)
        acc8(*(const uint4*)(part + (size_t)k * 524288 + (size_t)m * 4096 + c * 8), s);
    const int kb = c >> 2, qq = c & 3, mt = m >> 4, l16 = m & 15;
    u16 o8[8];
#pragma unroll
    for (int j = 0; j < 8; ++j) o8[j] = f2h_(s[j]);
    *(uint4*)(out + ((size_t)(kb * 8 + mt) * 64 + qq * 16 + l16) * 8) = *(const uint4*)o8;
}

__launch_bounds__(256)
__global__ void reduce_add_f32(const u16* __restrict__ part, const float* __restrict__ resin,
                               float* __restrict__ out, int SK) {
    const int idx = blockIdx.x * 256 + threadIdx.x;
    const size_t base = (size_t)idx * 8;
    float s[8];
    *(float4*)&s[0] = *(const float4*)(resin + base);
    *(float4*)&s[4] = *(const float4*)(resin + base + 4);
    for (int k = 0; k < SK; ++k)
        acc8(*(const uint4*)(part + (size_t)k * 524288 + base), s);
    *(float4*)(out + base)     = *(const float4*)&s[0];
    *(float4*)(out + base + 4) = *(const float4*)&s[4];
}

// ---------------------------------------------------------------------------
// Fused: res2 = resin + sum_k(part[k]); aout = rmsnorm(res2, w) in Afrag.
// One block per token row (128 blocks); thread t owns cols t*16..t*16+15.
// ---------------------------------------------------------------------------
__launch_bounds__(256)
__global__ void reduce_add_rms(const u16* __restrict__ part, const float* __restrict__ resin,
                               float* __restrict__ resout, const float* __restrict__ w,
                               u16* __restrict__ aout, int SK) {
    const int row = blockIdx.x, t = threadIdx.x;
    const size_t rb = (size_t)row * 4096;
    float s[16];
    {
        const size_t base = rb + (size_t)t * 16;
        *(float4*)&s[0]  = *(const float4*)(resin + base);
        *(float4*)&s[4]  = *(const float4*)(resin + base + 4);
        *(float4*)&s[8]  = *(const float4*)(resin + base + 8);
        *(float4*)&s[12] = *(const float4*)(resin + base + 12);
        for (int k = 0; k < SK; ++k) {
            const u16* pk = part + (size_t)k * 524288 + base;
            acc8(*(const uint4*)pk, &s[0]);
            acc8(*(const uint4*)(pk + 8), &s[8]);
        }
        float4* ro = (float4*)(resout + base);
        ro[0] = *(float4*)&s[0];  ro[1] = *(float4*)&s[4];
        ro[2] = *(float4*)&s[8];  ro[3] = *(float4*)&s[12];
    }
    float ss = 0.f;
#pragma unroll
    for (int j = 0; j < 16; ++j) ss += s[j] * s[j];
#pragma unroll
    for (int off = 32; off > 0; off >>= 1) ss += __shfl_down(ss, off, 64);
    __shared__ float ws4[4];
    if ((t & 63) == 0) ws4[t >> 6] = ss;
    __syncthreads();
    float total = ws4[0] + ws4[1] + ws4[2] + ws4[3];
    float r = rsqrtf(total * (1.f / 4096.f) + 1e-6f);
    const int mt = row >> 4, l16 = row & 15;
#pragma unroll
    for (int c2 = 0; c2 < 2; ++c2) {
        const int c = t * 2 + c2;
        const int kb = c >> 2, qq = c & 3;
        u16 o8[8];
#pragma unroll
        for (int j = 0; j < 8; ++j)
            o8[j] = f2h_(s[c2 * 8 + j] * r * w[c * 8 + j]);
        *(uint4*)(aout + ((size_t)(kb * 8 + mt) * 64 + qq * 16 + l16) * 8) = *(const uint4*)o8;
    }
}

__launch_bounds__(256)
__global__ void silu_mul(const u16* __restrict__ part, u16* __restrict__ act, int SK) {
    const int idx = blockIdx.x * 256 + threadIdx.x;
    const int m = idx / 1376, c = idx - m * 1376;
    const int nb = c * 8;
    float g[8] = {}, u[8] = {};
    for (int k = 0; k < SK; ++k) {
        const size_t base = (size_t)k * 2818048 + (size_t)m * 22016 + nb;
        acc8(*(const uint4*)(part + base), g);
        acc8(*(const uint4*)(part + base + 11008), u);
    }
    const int kb = nb >> 5, qq = (nb >> 3) & 3, mt = m >> 4, l16 = m & 15;
    u16 o8[8];
#pragma unroll
    for (int j = 0; j < 8; ++j) {
        float a = g[j] / (1.f + __expf(-g[j])) * u[j];
        o8[j] = f2h_(a);
    }
    *(uint4*)(act + ((size_t)(kb * 8 + mt) * 64 + qq * 16 + l16) * 8) = *(const uint4*)o8;
}

// ---------------------------------------------------------------------------
extern "C" void kernel_launch(void* const* d_in, const int* in_sizes, int n_in,
                              void* d_out, int out_size, void* d_ws, size_t ws_size,
                              hipStream_t stream) {
    const float* x      = (const float*)d_in[0];
    const float* ln1_w  = (const float*)d_in[1];
    const float* ln2_w  = (const float*)d_in[2];
    const int*   qkv_qw = (const int*)d_in[3];
    const int*   qkv_qz = (const int*)d_in[4];
    const float* qkv_sc = (const float*)d_in[5];
    const int*   o_qw   = (const int*)d_in[6];
    const int*   o_qz   = (const int*)d_in[7];
    const float* o_sc   = (const float*)d_in[8];
    const int*   gu_qw  = (const int*)d_in[9];
    const int*   gu_qz  = (const int*)d_in[10];
    const float* gu_sc  = (const float*)d_in[11];
    const int*   dn_qw  = (const int*)d_in[12];
    const int*   dn_qz  = (const int*)d_in[13];
    const float* dn_sc  = (const float*)d_in[14];
    float* out = (float*)d_out;

    // ws layout
    char* ws = (char*)d_ws;
    u16*   pbuf = (u16*)(ws);                 // partials: max 45.09 MB (gu SK8)
    u16*   act  = (u16*)(ws + 47906816);      // 2.75 MB fp16 (Afrag)
    float* res2 = (float*)(ws + 50724864);    // 2 MB fp32
    u16*   slot = (u16*)(ws + 52822016);      // 1 MB fp16 Afrag (h1/qb/h2)

    // h1 = rmsnorm(x, ln1) -> Afrag
    rmsnorm_k<<<128, 256, 0, stream>>>(x, ln1_w, slot);

    // q = h1 @ Wqkv[:, :4096]   (32 tiles x SK22, kchunk 192 -> 704 blocks)
    gemm_awq<<<dim3(32, 22), 256, 0, stream>>>(slot, qkv_qz, qkv_sc, qkv_qw, pbuf,
                                               1536, 1536, 12288, 4096, 4096, 192);
    reduce_to_afrag<<<256, 256, 0, stream>>>(pbuf, slot, 22);

    // attn = q @ Wo ; fused: res2 = x + attn, slot = rmsnorm(res2, ln2)
    gemm_awq<<<dim3(32, 22), 256, 0, stream>>>(slot, o_qz, o_sc, o_qw, pbuf,
                                               512, 512, 4096, 4096, 4096, 192);
    reduce_add_rms<<<128, 256, 0, stream>>>(pbuf, x, res2, ln2_w, slot, 22);

    // gate_up = h2 @ Wgu   (172 tiles x SK8, kchunk 512 -> 1376 blocks)
    gemm_awq<<<dim3(172, 8), 256, 0, stream>>>(slot, gu_qz, gu_sc, gu_qw, pbuf,
                                               2752, 2752, 22016, 22016, 4096, 512);
    silu_mul<<<688, 256, 0, stream>>>(pbuf, act, 8);

    // down = act @ Wdn   (32 tiles x SK22, kchunk 512 -> 704 blocks, 1 batch)
    gemm_awq<<<dim3(32, 22), 256, 0, stream>>>(act, dn_qz, dn_sc, dn_qw, pbuf,
                                               512, 512, 4096, 4096, 11008, 512);
    reduce_add_f32<<<256, 256, 0, stream>>>(pbuf, res2, out, 22);
}